// Round 11
// baseline (137.943 us; speedup 1.0000x reference)
//
#include <hip/hip_runtime.h>
#include <hip/hip_fp16.h>
#include <math.h>

#define NN 100000
#define NE 1600000
#define FIN 50
#define NC 16

#define NPB 256                        // nodes per bucket
#define NB  391                        // buckets
#define CAP 4608                       // slots/bucket (mean 4092 + 8 sigma)
#define NBLK 512                       // front blocks (1024 threads)
#define EPB (NE / NBLK)                // 3125 edges/block (exact)
#define KED ((EPB + 1023) / 1024)      // 4 reg-cached int2 edges/thread
#define KAGG ((CAP + 1023) / 1024)     // 5 reg-cached edges/thread

// ---------------------------------------------------------------------------
// ROUND-10 LESSON: cooperative path likely hung under graph capture
// ("container failed twice" after the launch became acceptable at 25KB LDS).
// Cooperative branch abandoned — this is the safe two-kernel form of the
// same phase bodies. kA: every block does place (EPB=3125, ei reg-cached,
// in-LDS counting sort, coalesced output) THEN lin (wave-per-node, zero
// LDS, zero barriers, weights in VGPRs, split-K shfl) — no place/lin block
// imbalance. kB: agg (r8-proven + early self-read + 8-wide gather).
// ---------------------------------------------------------------------------
__global__ __launch_bounds__(1024) void kA(
    const float* __restrict__ x,
    const float* __restrict__ W_l,
    const float* __restrict__ W_r,
    const int* __restrict__ ei,       // [2, NE]
    int* __restrict__ gcur_s,         // [NB*16] cursors (zeroed)
    unsigned* __restrict__ buf,       // [NB*CAP]
    __half* __restrict__ y_l,         // [NN*16]
    float* __restrict__ outv)         // self f32 [NN*NC]
{
    // h/lstart/lcur/gbase 4*391*4=6256B | slist 3125*4=12500B |
    // bid u16 3125*2=6250B = 25006B
    __shared__ __align__(16) char smem[25024];
    __shared__ int wsum[8];
    const int tid = threadIdx.x;
    const int bx  = blockIdx.x;

    // ======== place ========
    int* h      = (int*)smem;                 // [NB]
    int* lstart = h + NB;                     // [NB]
    int* lcur   = lstart + NB;                // [NB]
    int* gbase  = lcur + NB;                  // [NB]
    unsigned* slist = (unsigned*)(gbase + NB);            // [EPB]
    unsigned short* bid = (unsigned short*)(slist + EPB); // [EPB]

    if (tid < NB) h[tid] = 0;

    const int e0 = bx * EPB;

    // ei read ONCE into registers (static unroll -> VGPRs, rule #20)
    int2 er[KED];
#pragma unroll
    for (int k = 0; k < KED; ++k) {
        const int e = tid + (k << 10);
        if (e < EPB) { er[k].x = ei[e0 + e]; er[k].y = ei[NE + e0 + e]; }
    }
    __syncthreads();

    // pass 1: histogram (LDS atomics from registers)
#pragma unroll
    for (int k = 0; k < KED; ++k) {
        const int e = tid + (k << 10);
        if (e < EPB) atomicAdd(&h[((unsigned)er[k].y) >> 8], 1);
    }
    __syncthreads();

    // pass 2: exclusive scan of h[0..391), thread-per-bucket
    int own = 0, incl = 0;
    if (tid < NB) {
        own = h[tid];
        incl = own;
#pragma unroll
        for (int off = 1; off < 64; off <<= 1) {
            int t = __shfl_up(incl, off, 64);
            if ((tid & 63) >= off) incl += t;
        }
        if ((tid & 63) == 63) wsum[tid >> 6] = incl;
    }
    __syncthreads();
    if (tid < NB) {
        const int w = tid >> 6;
        int pfx = 0;
#pragma unroll
        for (int j = 0; j < 6; ++j)
            if (j < w) pfx += wsum[j];
        const int st = pfx + incl - own;
        lstart[tid] = st;
        lcur[tid]   = st;
        // pass 3 fused: global cursor reservation
        gbase[tid] = own ? atomicAdd(&gcur_s[tid * 16], own) : 0;
    }
    __syncthreads();

    // pass 4: counting-sort scatter into LDS (from registers)
#pragma unroll
    for (int k = 0; k < KED; ++k) {
        const int e = tid + (k << 10);
        if (e < EPB) {
            const int b = ((unsigned)er[k].y) >> 8;
            const int pos = atomicAdd(&lcur[b], 1);
            slist[pos] = (unsigned)er[k].x
                       | ((unsigned)(er[k].y & 255) << 17);
            bid[pos] = (unsigned short)b;
        }
    }
    __syncthreads();

    // pass 5: coalesced output (runs within each bucket)
    for (int i = tid; i < EPB; i += 1024) {
        const unsigned v = slist[i];
        const int b = bid[i];
        const int goff = gbase[b] + (i - lstart[b]);
        if (goff < CAP)
            buf[(size_t)b * CAP + goff] = v;
    }

    // ======== lin: wave-per-node, zero LDS, zero barriers ========
    const int lane = tid & 63;
    const int col  = lane & 31;               // output column 0..31
    const int kh   = lane >> 5;               // k-half: 0 -> [0,26), 1 -> [26,50)
    const int nf2  = 13 - kh;                 // 13 or 12 float2
    const float* Wrow = ((col < 16) ? (W_l + col * FIN)
                                    : (W_r + (col - 16) * FIN)) + kh * 26;
    float wreg[26];
    {
        const float2* w2 = (const float2*)Wrow;
#pragma unroll
        for (int j = 0; j < 13; ++j)
            if (j < nf2) {
                float2 t = w2[j];
                wreg[2 * j]     = t.x;
                wreg[2 * j + 1] = t.y;
            }
    }
    const int gw = bx * 16 + (tid >> 6);      // 0..8191
    for (int n = gw; n < NN; n += NBLK * 16) {
        const float2* x2 = (const float2*)(x + (size_t)n * FIN) + kh * 13;
        float acc = 0.f;
#pragma unroll
        for (int j = 0; j < 13; ++j)
            if (j < nf2) {
                const float2 t = x2[j];
                acc = fmaf(t.x, wreg[2 * j], acc);
                acc = fmaf(t.y, wreg[2 * j + 1], acc);
            }
        acc += __shfl_xor(acc, 32, 64);       // combine the two k-halves
        if (kh == 0) {
            if (col < 16)
                y_l[(size_t)n * 16 + col] = __float2half(acc);
            else
                outv[(size_t)n * NC + (col - 16)] = acc;
        }
    }
}

// ---------------------------------------------------------------------------
// Aggregation: one 1024-thread block per bucket. buf reg-cached (read once),
// early self-read, in-LDS counting sort, 256-wide scan, register
// segment-reduce with 8-wide gather unroll, fused epilogue.
// ---------------------------------------------------------------------------
__global__ __launch_bounds__(1024) void kB(
    const int* __restrict__ gcur_s,
    const unsigned* __restrict__ buf,
    const uint2* __restrict__ y2,     // y_l as uint2[NN*4]
    const float* __restrict__ b_l,
    float* __restrict__ logp,
    float* __restrict__ outv)         // self on entry, final out on exit
{
    __shared__ unsigned slist[CAP];   // 18.4 KB
    __shared__ int lcnt[NPB];
    __shared__ int scur[NPB];
    __shared__ int sstart[NPB];
    __shared__ int wsum[4];
    __shared__ float sb[NC];

    const int tid = threadIdx.x;
    const int tl = tid >> 2;
    const int q  = tid & 3;
    const int bx = blockIdx.x;
    const int n  = bx * NPB + tl;

    // EARLY: issue self read; consumed only in the epilogue
    float4 sf = make_float4(0.f, 0.f, 0.f, 0.f);
    if (n < NN) sf = ((const float4*)(outv + (size_t)n * NC))[q];

    if (tid < NPB) lcnt[tid] = 0;
    if (tid < NC) sb[tid] = b_l[tid];
    __syncthreads();

    int cnt = gcur_s[bx * 16];
    if (cnt > CAP) cnt = CAP;
    const size_t base = (size_t)bx * CAP;

    // buf read ONCE into registers
    unsigned ev[KAGG];
#pragma unroll
    for (int k = 0; k < KAGG; ++k) {
        const int i = tid + (k << 10);
        if (i < cnt) ev[k] = buf[base + i];
    }

    // pass 1: per-local-node counts
#pragma unroll
    for (int k = 0; k < KAGG; ++k) {
        const int i = tid + (k << 10);
        if (i < cnt) atomicAdd(&lcnt[ev[k] >> 17], 1);
    }
    __syncthreads();

    // pass 2: 256-wide exclusive scan
    int own = 0, incl = 0;
    if (tid < NPB) {
        own = lcnt[tid];
        incl = own;
#pragma unroll
        for (int off = 1; off < 64; off <<= 1) {
            int t = __shfl_up(incl, off, 64);
            if ((tid & 63) >= off) incl += t;
        }
        if ((tid & 63) == 63) wsum[tid >> 6] = incl;
    }
    __syncthreads();
    if (tid < NPB) {
        const int w = tid >> 6;
        int pfx = 0;
        if (w > 0) pfx += wsum[0];
        if (w > 1) pfx += wsum[1];
        if (w > 2) pfx += wsum[2];
        const int st = pfx + incl - own;
        sstart[tid] = st;
        scur[tid]   = st;
    }
    __syncthreads();

    // pass 3: scatter src ids into sorted slots (from registers)
#pragma unroll
    for (int k = 0; k < KAGG; ++k) {
        const int i = tid + (k << 10);
        if (i < cnt) {
            const unsigned v = ev[k];
            const int pos = atomicAdd(&scur[v >> 17], 1);
            slist[pos] = v & 0x1FFFF;
        }
    }
    __syncthreads();

    // pass 4: register segment-reduce, 8-wide gather unroll
    if (n >= NN) return;

    const int seg0 = sstart[tl];
    const int deg  = lcnt[tl];
    const int seg1 = seg0 + deg;

    float a0 = 0.f, a1 = 0.f, a2 = 0.f, a3 = 0.f;
    int i = seg0;
    for (; i + 8 <= seg1; i += 8) {
        uint2 g[8];
#pragma unroll
        for (int u = 0; u < 8; ++u)
            g[u] = y2[slist[i + u] * 4 + q];
#pragma unroll
        for (int u = 0; u < 8; ++u) {
            float2 lo = __half22float2(__builtin_bit_cast(__half2, g[u].x));
            float2 hi = __half22float2(__builtin_bit_cast(__half2, g[u].y));
            a0 += lo.x; a1 += lo.y; a2 += hi.x; a3 += hi.y;
        }
    }
    for (; i < seg1; ++i) {
        uint2 qa = y2[slist[i] * 4 + q];
        float2 lo = __half22float2(__builtin_bit_cast(__half2, qa.x));
        float2 hi = __half22float2(__builtin_bit_cast(__half2, qa.y));
        a0 += lo.x; a1 += lo.y; a2 += hi.x; a3 += hi.y;
    }

    // pass 5: fused epilogue, width-4 shfl reductions
    float inv = 1.0f / fmaxf((float)deg, 1.0f);
    float v0 = a0 * inv + sb[4 * q + 0] + sf.x;
    float v1 = a1 * inv + sb[4 * q + 1] + sf.y;
    float v2 = a2 * inv + sb[4 * q + 2] + sf.z;
    float v3 = a3 * inv + sb[4 * q + 3] + sf.w;

    float m = fmaxf(fmaxf(v0, v1), fmaxf(v2, v3));
    m = fmaxf(m, __shfl_xor(m, 1, 4));
    m = fmaxf(m, __shfl_xor(m, 2, 4));
    float es = expf(v0 - m) + expf(v1 - m) + expf(v2 - m) + expf(v3 - m);
    es += __shfl_xor(es, 1, 4);
    es += __shfl_xor(es, 2, 4);
    float lse = m + logf(es);

    ((float4*)(outv + (size_t)n * NC))[q] = make_float4(v0, v1, v2, v3);
    ((float4*)(logp + (size_t)n * NC))[q] =
        make_float4(v0 - lse, v1 - lse, v2 - lse, v3 - lse);
}

extern "C" void kernel_launch(void* const* d_in, const int* in_sizes, int n_in,
                              void* d_out, int out_size, void* d_ws, size_t ws_size,
                              hipStream_t stream) {
    const float* x   = (const float*)d_in[0];
    const int*   ei  = (const int*)d_in[1];
    const float* W_l = (const float*)d_in[2];
    const float* b_l = (const float*)d_in[3];
    const float* W_r = (const float*)d_in[4];

    float* logp = (float*)d_out;                    // [NN*NC]
    float* outv = (float*)d_out + (size_t)NN * NC;  // [NN*NC], self scratch

    // ws: y_l half[NN*16] (3.2MB) | buf u32[NB*CAP] (7.2MB) | gcur_s[NB*16]
    __half* y_l   = (__half*)d_ws;
    unsigned* buf = (unsigned*)(y_l + (size_t)NN * 16);
    int* gcur_s   = (int*)(buf + (size_t)NB * CAP);

    hipMemsetAsync(gcur_s, 0, (size_t)NB * 16 * sizeof(int), stream);

    kA<<<NBLK, 1024, 0, stream>>>(x, W_l, W_r, ei, gcur_s, buf, y_l, outv);
    kB<<<NB, 1024, 0, stream>>>(gcur_s, buf, (const uint2*)y_l, b_l, logp, outv);
}